// Round 2
// baseline (463.548 us; speedup 1.0000x reference)
//
#include <hip/hip_runtime.h>
#include <hip/hip_bf16.h>

#define N_NODES 50000
#define N_EDGES 800000
#define DIM 256

typedef __attribute__((ext_vector_type(8))) short short8;
typedef __attribute__((ext_vector_type(4))) float floatx4;
typedef unsigned short u16;
typedef unsigned int u32;

__device__ __forceinline__ u16 f2bf(float f) {
    u32 u = __float_as_uint(f);
    u += 0x7FFFu + ((u >> 16) & 1u);   // RNE
    return (u16)(u >> 16);
}
__device__ __forceinline__ float bf_lo(u32 u) { return __uint_as_float(u << 16); }
__device__ __forceinline__ float bf_hi(u32 u) { return __uint_as_float(u & 0xFFFF0000u); }
__device__ __forceinline__ u32 pack_bf(float lo, float hi) {
    return (u32)f2bf(lo) | ((u32)f2bf(hi) << 16);
}

// ---------------- W transpose + bf16 convert: wT[j][k] = W_g[k][j] ----------------
__global__ void conv_w_kernel(const float* __restrict__ W, const float* __restrict__ U,
                              const float* __restrict__ V, u16* __restrict__ wT) {
    int j = blockIdx.x;          // 0..767 (global output column)
    int k = threadIdx.x;         // 0..255
    int g = j >> 8, jc = j & 255;
    const float* M = (g == 0) ? W : ((g == 1) ? U : V);
    wT[(size_t)j * 256 + k] = f2bf(M[(size_t)k * 256 + jc]);
}

// ---------------- degree histogram ----------------
__global__ void hist_kernel(const int* __restrict__ dst, int* __restrict__ deg) {
    int e = blockIdx.x * 256 + threadIdx.x;
    if (e < N_EDGES) atomicAdd(&deg[dst[e]], 1);
}

// ---------------- exclusive scan (single block) ----------------
__global__ void scan_kernel(const int* __restrict__ deg, int* __restrict__ row_start,
                            int* __restrict__ cursor, int n) {
    __shared__ int part[1024];
    int t = threadIdx.x;
    int chunk = (n + 1023) >> 10;
    int s = t * chunk, e = min(s + chunk, n);
    int acc = 0;
    for (int i = s; i < e; ++i) acc += deg[i];
    part[t] = acc;
    __syncthreads();
    for (int off = 1; off < 1024; off <<= 1) {
        int v = (t >= off) ? part[t - off] : 0;
        __syncthreads();
        part[t] += v;
        __syncthreads();
    }
    int run = part[t] - acc;   // exclusive prefix
    for (int i = s; i < e; ++i) {
        row_start[i] = run;
        cursor[i] = run;
        run += deg[i];
    }
    if (t == 1023) row_start[n] = part[1023];
}

// ---------------- scatter edges into CSR-by-dst ----------------
__global__ void scatter_kernel(const int* __restrict__ src, const int* __restrict__ dst,
                               int* __restrict__ cursor, int* __restrict__ esrc) {
    int e = blockIdx.x * 256 + threadIdx.x;
    if (e < N_EDGES) {
        int d = dst[e];
        int pos = atomicAdd(&cursor[d], 1);
        esrc[pos] = src[e];
    }
}

// ---------------- fused 3-way GEMM: [N,256] x [256,768] -> Wh(bf16)/Uh(f32->d_out)/Vh(bf16) ----------------
// A = x (fp32, converted to bf16 during staging), B^T = wT (bf16, [768][256])
__global__ __launch_bounds__(256) void gemm_kernel(
    const float* __restrict__ x, const u16* __restrict__ wT,
    const float* __restrict__ Wb, const float* __restrict__ Ub, const float* __restrict__ Vb,
    u16* __restrict__ Wh, float* __restrict__ Uh_f32, u16* __restrict__ Vh, int n) {
    __shared__ __align__(16) u16 As[64 * 32];
    __shared__ __align__(16) u16 Bs[64 * 32];

    int rb = blockIdx.x * 64;
    int cb = blockIdx.y * 64;
    int t = threadIdx.x, lane = t & 63, w = t >> 6;
    int wm = w >> 1, wn = w & 1;

    floatx4 acc[2][2] = {};
    int sr = t >> 2, sq = t & 3;   // staging: row 0..63, 16B-quad 0..3

    for (int k0 = 0; k0 < 256; k0 += 32) {
        // stage A (convert fp32 -> bf16 on the fly), XOR-swizzled quads
        uint4 av = {0, 0, 0, 0};
        int gr = rb + sr;
        if (gr < n) {
            const float* px = x + (size_t)gr * 256 + k0 + sq * 8;
            floatx4 f0 = *(const floatx4*)(px);
            floatx4 f1 = *(const floatx4*)(px + 4);
            av.x = pack_bf(f0[0], f0[1]);
            av.y = pack_bf(f0[2], f0[3]);
            av.z = pack_bf(f1[0], f1[1]);
            av.w = pack_bf(f1[2], f1[3]);
        }
        uint4 bv = *(const uint4*)(wT + (size_t)(cb + sr) * 256 + k0 + sq * 8);
        *(uint4*)(&As[sr * 32 + ((sq ^ (sr & 3)) * 8)]) = av;
        *(uint4*)(&Bs[sr * 32 + ((sq ^ (sr & 3)) * 8)]) = bv;
        __syncthreads();

        int kq = lane >> 4;
        short8 a[2], b[2];
#pragma unroll
        for (int i = 0; i < 2; ++i) {
            int ar = wm * 32 + i * 16 + (lane & 15);
            a[i] = *(short8*)(&As[ar * 32 + ((kq ^ (ar & 3)) * 8)]);
            int br = wn * 32 + i * 16 + (lane & 15);
            b[i] = *(short8*)(&Bs[br * 32 + ((kq ^ (br & 3)) * 8)]);
        }
#pragma unroll
        for (int i = 0; i < 2; ++i)
#pragma unroll
            for (int j = 0; j < 2; ++j)
                acc[i][j] = __builtin_amdgcn_mfma_f32_16x16x32_bf16(a[i], b[j], acc[i][j], 0, 0, 0);
        __syncthreads();
    }

    int g = cb >> 8;
    int cwb = cb & 255;
    const float* bias = (g == 0) ? Wb : ((g == 1) ? Ub : Vb);
#pragma unroll
    for (int i = 0; i < 2; ++i)
#pragma unroll
        for (int j = 0; j < 2; ++j) {
            int col = cwb + wn * 32 + j * 16 + (lane & 15);
            float bvv = bias[col];
#pragma unroll
            for (int r = 0; r < 4; ++r) {
                int row = rb + wm * 32 + i * 16 + (lane >> 4) * 4 + r;
                if (row < n) {
                    float val = acc[i][j][r] + bvv;
                    if (g == 0)      Wh[(size_t)row * 256 + col] = f2bf(val);
                    else if (g == 1) Uh_f32[(size_t)row * 256 + col] = val;
                    else             Vh[(size_t)row * 256 + col] = f2bf(val);
                }
            }
        }
}

// ---------------- node-centric aggregate + LN + ReLU + residual ----------------
// Uh comes in fp32 via `inout` (== d_out); each thread reads its own slice then
// overwrites it with the final result. Same-stream ordering makes this safe.
__global__ __launch_bounds__(256) void node_kernel(
    const u16* __restrict__ Wh, const u16* __restrict__ Vh,
    const float* __restrict__ x, const int* __restrict__ row_start, const int* __restrict__ esrc,
    const float* __restrict__ attn_l, const float* __restrict__ attn_r,
    const float* __restrict__ gamma, const float* __restrict__ beta,
    float* inout, int n) {
    int wv = threadIdx.x >> 6, lane = threadIdx.x & 63;
    int v = blockIdx.x * 4 + wv;
    if (v >= n) return;
    int c0 = lane * 4;

    floatx4 al = *(const floatx4*)(attn_l + c0);
    floatx4 ar = *(const floatx4*)(attn_r + c0);

    uint2 wvv = *(const uint2*)(Wh + (size_t)v * 256 + c0);
    float td[4] = { bf_lo(wvv.x) * ar[0], bf_hi(wvv.x) * ar[1],
                    bf_lo(wvv.y) * ar[2], bf_hi(wvv.y) * ar[3] };

    float acc_h[4] = {0.f, 0.f, 0.f, 0.f};
    float acc_s[4] = {0.f, 0.f, 0.f, 0.f};

    int e0 = row_start[v], e1 = row_start[v + 1];
    for (int e = e0; e < e1; ++e) {
        int u = esrc[e];
        uint2 wu = *(const uint2*)(Wh + (size_t)u * 256 + c0);
        uint2 vu = *(const uint2*)(Vh + (size_t)u * 256 + c0);
        float wf[4] = { bf_lo(wu.x), bf_hi(wu.x), bf_lo(wu.y), bf_hi(wu.y) };
        float vf[4] = { bf_lo(vu.x), bf_hi(vu.x), bf_lo(vu.y), bf_hi(vu.y) };
#pragma unroll
        for (int j = 0; j < 4; ++j) {
            float tt = wf[j] * al[j] + td[j];
            float s = 1.0f / (1.0f + __expf(-tt));
            acc_s[j] += s;
            acc_h[j] += s * vf[j];
        }
    }

    floatx4 uh = *(const floatx4*)(inout + (size_t)v * 256 + c0);
    float h[4];
#pragma unroll
    for (int j = 0; j < 4; ++j) h[j] = uh[j] + acc_h[j] / (acc_s[j] + 1e-6f);

    float s01 = h[0] + h[1] + h[2] + h[3];
#pragma unroll
    for (int m = 32; m; m >>= 1) s01 += __shfl_xor(s01, m, 64);
    float mu = s01 * (1.0f / 256.0f);
    float d[4] = { h[0] - mu, h[1] - mu, h[2] - mu, h[3] - mu };
    float sq = d[0] * d[0] + d[1] * d[1] + d[2] * d[2] + d[3] * d[3];
#pragma unroll
    for (int m = 32; m; m >>= 1) sq += __shfl_xor(sq, m, 64);
    float inv = rsqrtf(sq * (1.0f / 256.0f) + 1e-6f);

    floatx4 gm = *(const floatx4*)(gamma + c0);
    floatx4 bt = *(const floatx4*)(beta + c0);
    floatx4 xr = *(const floatx4*)(x + (size_t)v * 256 + c0);
    floatx4 res;
#pragma unroll
    for (int j = 0; j < 4; ++j) {
        float y = d[j] * inv * gm[j] + bt[j];
        y = fmaxf(y, 0.0f);
        res[j] = xr[j] + y;
    }
    *(floatx4*)(inout + (size_t)v * 256 + c0) = res;
}

extern "C" void kernel_launch(void* const* d_in, const int* in_sizes, int n_in,
                              void* d_out, int out_size, void* d_ws, size_t ws_size,
                              hipStream_t stream) {
    const float* x       = (const float*)d_in[0];
    const int*   src     = (const int*)d_in[1];    // harness converts int64 -> int32
    const int*   dst     = (const int*)d_in[2];
    const float* W_w     = (const float*)d_in[3];
    const float* W_b     = (const float*)d_in[4];
    const float* U_w     = (const float*)d_in[5];
    const float* U_b     = (const float*)d_in[6];
    const float* V_w     = (const float*)d_in[7];
    const float* V_b     = (const float*)d_in[8];
    const float* attn_l  = (const float*)d_in[9];
    const float* attn_r  = (const float*)d_in[10];
    const float* gamma   = (const float*)d_in[11];
    const float* beta    = (const float*)d_in[12];

    char* ws = (char*)d_ws;
    size_t off = 0;
    auto alloc = [&](size_t bytes) -> char* {
        char* p = ws + off;
        off += (bytes + 255) & ~(size_t)255;
        return p;
    };
    u16* Wh      = (u16*)alloc((size_t)N_NODES * DIM * 2);
    u16* Vh      = (u16*)alloc((size_t)N_NODES * DIM * 2);
    u16* wT      = (u16*)alloc((size_t)768 * 256 * 2);
    int* deg     = (int*)alloc((size_t)N_NODES * 4);
    int* rows    = (int*)alloc((size_t)(N_NODES + 1) * 4);
    int* cursor  = (int*)alloc((size_t)N_NODES * 4);
    int* esrc    = (int*)alloc((size_t)N_EDGES * 4);

    float* Uh_f32 = (float*)d_out;   // staged in d_out, overwritten by node_kernel

    hipMemsetAsync(deg, 0, (size_t)N_NODES * 4, stream);

    conv_w_kernel<<<768, 256, 0, stream>>>(W_w, U_w, V_w, wT);
    hist_kernel<<<(N_EDGES + 255) / 256, 256, 0, stream>>>(dst, deg);
    scan_kernel<<<1, 1024, 0, stream>>>(deg, rows, cursor, N_NODES);
    scatter_kernel<<<(N_EDGES + 255) / 256, 256, 0, stream>>>(src, dst, cursor, esrc);

    dim3 gg((N_NODES + 63) / 64, 12);
    gemm_kernel<<<gg, 256, 0, stream>>>(x, wT, W_b, U_b, V_b, Wh, Uh_f32, Vh, N_NODES);

    node_kernel<<<(N_NODES + 3) / 4, 256, 0, stream>>>(
        Wh, Vh, x, rows, esrc, attn_l, attn_r, gamma, beta, (float*)d_out, N_NODES);
}

// Round 3
// 339.254 us; speedup vs baseline: 1.3664x; 1.3664x over previous
//
#include <hip/hip_runtime.h>
#include <hip/hip_bf16.h>

#define NN 50000
#define NE 800000
#define NB 196          // ceil(NN/256)

typedef __attribute__((ext_vector_type(8))) short short8;
typedef __attribute__((ext_vector_type(4))) float floatx4;
typedef unsigned short u16;
typedef unsigned int u32;

__device__ __forceinline__ u16 f2bf(float f) {
    u32 u = __float_as_uint(f);
    u += 0x7FFFu + ((u >> 16) & 1u);   // RNE
    return (u16)(u >> 16);
}
__device__ __forceinline__ float bf_lo(u32 u) { return __uint_as_float(u << 16); }
__device__ __forceinline__ float bf_hi(u32 u) { return __uint_as_float(u & 0xFFFF0000u); }
__device__ __forceinline__ u32 pack_bf(float lo, float hi) {
    return (u32)f2bf(lo) | ((u32)f2bf(hi) << 16);
}
__device__ __forceinline__ void gl_lds16(const void* g, void* l) {
    __builtin_amdgcn_global_load_lds((const __attribute__((address_space(1))) void*)g,
                                     (__attribute__((address_space(3))) void*)l, 16, 0, 0);
}

// ---------------- W/U/V transpose + bf16: wT[g*256 + j][k] = M_g[k][j] ----------------
__global__ __launch_bounds__(256) void tw_kernel(const float* __restrict__ W, const float* __restrict__ U,
                                                 const float* __restrict__ V, u16* __restrict__ wT) {
    __shared__ float s[32][33];
    int g = blockIdx.z;
    const float* M = (g == 0) ? W : ((g == 1) ? U : V);
    int r0 = blockIdx.x * 32, c0 = blockIdx.y * 32;
    int tx = threadIdx.x & 31, ty = threadIdx.x >> 5;   // 32 x 8
#pragma unroll
    for (int k = 0; k < 4; ++k)
        s[ty + k * 8][tx] = M[(size_t)(r0 + ty + k * 8) * 256 + c0 + tx];
    __syncthreads();
#pragma unroll
    for (int k = 0; k < 4; ++k)
        wT[(size_t)(g * 256 + c0 + ty + k * 8) * 256 + r0 + tx] = f2bf(s[tx][ty + k * 8]);
}

// ---------------- degree histogram ----------------
__global__ void hist_kernel(const int* __restrict__ dst, int* __restrict__ deg) {
    int e = blockIdx.x * 256 + threadIdx.x;
    if (e < NE) atomicAdd(&deg[dst[e]], 1);
}

// ---------------- 3-phase scan ----------------
__global__ __launch_bounds__(256) void scanA_kernel(const int* __restrict__ deg, int* __restrict__ bsum) {
    int t = threadIdx.x;
    int i = blockIdx.x * 256 + t;
    int v = (i < NN) ? deg[i] : 0;
#pragma unroll
    for (int m = 32; m; m >>= 1) v += __shfl_xor(v, m, 64);
    __shared__ int ws[4];
    if ((t & 63) == 0) ws[t >> 6] = v;
    __syncthreads();
    if (t == 0) bsum[blockIdx.x] = ws[0] + ws[1] + ws[2] + ws[3];
}

__global__ __launch_bounds__(256) void scanB_kernel(const int* __restrict__ bsum, int* __restrict__ bpre,
                                                    int* __restrict__ rows_end) {
    int t = threadIdx.x, lane = t & 63, wv = t >> 6;
    int v = (t < NB) ? bsum[t] : 0;
    int inc = v;
#pragma unroll
    for (int off = 1; off < 64; off <<= 1) {
        int u = __shfl_up(inc, off, 64);
        if (lane >= off) inc += u;
    }
    __shared__ int wsum[4];
    if (lane == 63) wsum[wv] = inc;
    __syncthreads();
    int woff = 0;
    for (int k = 0; k < wv; ++k) woff += wsum[k];
    if (t < NB) bpre[t] = woff + inc - v;
    if (t == 255) rows_end[0] = woff + inc;   // total edge count
}

__global__ __launch_bounds__(256) void scanC_kernel(const int* __restrict__ deg, const int* __restrict__ bpre,
                                                    int* __restrict__ rows, int* __restrict__ cursor) {
    int t = threadIdx.x, lane = t & 63, wv = t >> 6;
    int i = blockIdx.x * 256 + t;
    int v = (i < NN) ? deg[i] : 0;
    int inc = v;
#pragma unroll
    for (int off = 1; off < 64; off <<= 1) {
        int u = __shfl_up(inc, off, 64);
        if (lane >= off) inc += u;
    }
    __shared__ int wsum[4];
    if (lane == 63) wsum[wv] = inc;
    __syncthreads();
    int woff = bpre[blockIdx.x];
    for (int k = 0; k < wv; ++k) woff += wsum[k];
    int excl = woff + inc - v;
    if (i < NN) { rows[i] = excl; cursor[i] = excl; }
}

// ---------------- scatter edges into CSR-by-dst ----------------
__global__ void scatter_kernel(const int* __restrict__ src, const int* __restrict__ dst,
                               int* __restrict__ cursor, int* __restrict__ esrc) {
    int e = blockIdx.x * 256 + threadIdx.x;
    if (e < NE) {
        int d = dst[e];
        int pos = atomicAdd(&cursor[d], 1);
        esrc[pos] = src[e];
    }
}

// ---------------- fused 3-way GEMM: [N,256] x [256,768], 128x128 tile, BK=64 ----------------
// A: reg-staged from fp32 x (bf16 pack + XOR-swizzled ds_write)
// B: global_load_lds direct from wT (pre-swizzled source address)
// out: g==0 -> WVh[:, 0:256] bf16, g==1 -> Uh f32 (d_out), g==2 -> WVh[:, 256:512] bf16
__global__ __launch_bounds__(256) void gemm_kernel(
    const float* __restrict__ x, const u16* __restrict__ wT,
    const float* __restrict__ Wb, const float* __restrict__ Ub, const float* __restrict__ Vb,
    u16* __restrict__ WVh, float* __restrict__ Uh) {
    __shared__ __align__(16) u16 As[128 * 64];
    __shared__ __align__(16) u16 Bs[128 * 64];

    int rb = blockIdx.x * 128;
    int cbg = blockIdx.y * 128;           // 0..640
    int t = threadIdx.x, lane = t & 63, w = t >> 6;
    int wm = w >> 1, wn = w & 1;

    floatx4 acc[4][4] = {};

    // B staging geometry (global_load_lds): inst covers 8 rows of 128B
    int b_subrow = lane >> 3;             // 0..7
    int b_q = lane & 7;                   // 16B quad within row
    // A staging geometry (reg path): thread -> (row, 32-elem half)
    int a_row = t >> 1;
    int a_half = t & 1;

    for (int kt = 0; kt < 4; ++kt) {
        int k0 = kt * 64;
        // ---- B: 4 global_load_lds per wave ----
#pragma unroll
        for (int ii = 0; ii < 4; ++ii) {
            int rowbase = (w * 4 + ii) * 8;
            int row = rowbase + b_subrow;
            int qa = b_q ^ (row & 7);
            gl_lds16(wT + (size_t)(cbg + row) * 256 + k0 + qa * 8, Bs + rowbase * 64);
        }
        // ---- A: load 32 fp32, pack to bf16, swizzled ds_write ----
        int grow = rb + a_row;
        uint4 pk[4] = {};
        if (grow < NN) {
            const float* px = x + (size_t)grow * 256 + k0 + a_half * 32;
#pragma unroll
            for (int c = 0; c < 4; ++c) {
                floatx4 f0 = *(const floatx4*)(px + c * 8);
                floatx4 f1 = *(const floatx4*)(px + c * 8 + 4);
                pk[c].x = pack_bf(f0[0], f0[1]);
                pk[c].y = pack_bf(f0[2], f0[3]);
                pk[c].z = pack_bf(f1[0], f1[1]);
                pk[c].w = pack_bf(f1[2], f1[3]);
            }
        }
#pragma unroll
        for (int c = 0; c < 4; ++c) {
            int q = a_half * 4 + c;
            *(uint4*)(As + a_row * 64 + ((q ^ (a_row & 7)) * 8)) = pk[c];
        }
        __syncthreads();

#pragma unroll
        for (int s = 0; s < 2; ++s) {
            short8 a[4], b[4];
#pragma unroll
            for (int i = 0; i < 4; ++i) {
                int ar = wm * 64 + i * 16 + (lane & 15);
                int q = s * 4 + (lane >> 4);
                a[i] = *(const short8*)(As + ar * 64 + ((q ^ (ar & 7)) * 8));
                int br = wn * 64 + i * 16 + (lane & 15);
                b[i] = *(const short8*)(Bs + br * 64 + ((q ^ (br & 7)) * 8));
            }
#pragma unroll
            for (int i = 0; i < 4; ++i)
#pragma unroll
                for (int j = 0; j < 4; ++j)
                    acc[i][j] = __builtin_amdgcn_mfma_f32_16x16x32_bf16(a[i], b[j], acc[i][j], 0, 0, 0);
        }
        __syncthreads();
    }

    int g = cbg >> 8;                    // 0,0,1,1,2,2
    int cloc = cbg & 255;                // 0 or 128
    const float* bias = (g == 0) ? Wb : ((g == 1) ? Ub : Vb);
#pragma unroll
    for (int i = 0; i < 4; ++i)
#pragma unroll
        for (int j = 0; j < 4; ++j) {
            int col = cloc + wn * 64 + j * 16 + (lane & 15);
            float bv = bias[col];
#pragma unroll
            for (int r = 0; r < 4; ++r) {
                int row = rb + wm * 64 + i * 16 + (lane >> 4) * 4 + r;
                if (row < NN) {
                    float val = acc[i][j][r] + bv;
                    if (g == 0)      WVh[(size_t)row * 512 + col] = f2bf(val);
                    else if (g == 1) Uh[(size_t)row * 256 + col] = val;
                    else             WVh[(size_t)row * 512 + 256 + col] = f2bf(val);
                }
            }
        }
}

// ---------------- node-centric aggregate + LN + ReLU + residual ----------------
// Uh comes in fp32 via inout (== d_out); overwritten with the final result.
__global__ __launch_bounds__(256) void node_kernel(
    const u16* __restrict__ WVh, const float* __restrict__ x,
    const int* __restrict__ rows, const int* __restrict__ esrc,
    const float* __restrict__ attn_l, const float* __restrict__ attn_r,
    const float* __restrict__ gamma, const float* __restrict__ beta,
    float* inout) {
    int wv = threadIdx.x >> 6, lane = threadIdx.x & 63;
    int v = blockIdx.x * 4 + wv;
    if (v >= NN) return;
    int c0 = lane * 4;

    floatx4 al = *(const floatx4*)(attn_l + c0);
    floatx4 ar = *(const floatx4*)(attn_r + c0);

    uint2 wvv = *(const uint2*)(WVh + (size_t)v * 512 + c0);
    float td[4] = { bf_lo(wvv.x) * ar[0], bf_hi(wvv.x) * ar[1],
                    bf_lo(wvv.y) * ar[2], bf_hi(wvv.y) * ar[3] };

    float acc_h[4] = {0.f, 0.f, 0.f, 0.f};
    float acc_s[4] = {0.f, 0.f, 0.f, 0.f};

    int e0 = rows[v], e1 = rows[v + 1];
    for (int e = e0; e < e1; ++e) {
        int u = esrc[e];
        const u16* base = WVh + (size_t)u * 512 + c0;
        uint2 wu = *(const uint2*)(base);
        uint2 vu = *(const uint2*)(base + 256);
        float wf[4] = { bf_lo(wu.x), bf_hi(wu.x), bf_lo(wu.y), bf_hi(wu.y) };
        float vf[4] = { bf_lo(vu.x), bf_hi(vu.x), bf_lo(vu.y), bf_hi(vu.y) };
#pragma unroll
        for (int j = 0; j < 4; ++j) {
            float tt = fmaf(wf[j], al[j], td[j]);
            float s = __builtin_amdgcn_rcpf(1.0f + __expf(-tt));
            acc_s[j] += s;
            acc_h[j] = fmaf(s, vf[j], acc_h[j]);
        }
    }

    floatx4 uh = *(const floatx4*)(inout + (size_t)v * 256 + c0);
    float h[4];
#pragma unroll
    for (int j = 0; j < 4; ++j)
        h[j] = uh[j] + acc_h[j] * __builtin_amdgcn_rcpf(acc_s[j] + 1e-6f);

    float s01 = h[0] + h[1] + h[2] + h[3];
#pragma unroll
    for (int m = 32; m; m >>= 1) s01 += __shfl_xor(s01, m, 64);
    float mu = s01 * (1.0f / 256.0f);
    float d[4] = { h[0] - mu, h[1] - mu, h[2] - mu, h[3] - mu };
    float sq = d[0] * d[0] + d[1] * d[1] + d[2] * d[2] + d[3] * d[3];
#pragma unroll
    for (int m = 32; m; m >>= 1) sq += __shfl_xor(sq, m, 64);
    float inv = rsqrtf(sq * (1.0f / 256.0f) + 1e-6f);

    floatx4 gm = *(const floatx4*)(gamma + c0);
    floatx4 bt = *(const floatx4*)(beta + c0);
    floatx4 xr = *(const floatx4*)(x + (size_t)v * 256 + c0);
    floatx4 res;
#pragma unroll
    for (int j = 0; j < 4; ++j) {
        float y = d[j] * inv * gm[j] + bt[j];
        y = fmaxf(y, 0.0f);
        res[j] = xr[j] + y;
    }
    *(floatx4*)(inout + (size_t)v * 256 + c0) = res;
}

extern "C" void kernel_launch(void* const* d_in, const int* in_sizes, int n_in,
                              void* d_out, int out_size, void* d_ws, size_t ws_size,
                              hipStream_t stream) {
    const float* x       = (const float*)d_in[0];
    const int*   src     = (const int*)d_in[1];    // harness converts int64 -> int32
    const int*   dst     = (const int*)d_in[2];
    const float* W_w     = (const float*)d_in[3];
    const float* W_b     = (const float*)d_in[4];
    const float* U_w     = (const float*)d_in[5];
    const float* U_b     = (const float*)d_in[6];
    const float* V_w     = (const float*)d_in[7];
    const float* V_b     = (const float*)d_in[8];
    const float* attn_l  = (const float*)d_in[9];
    const float* attn_r  = (const float*)d_in[10];
    const float* gamma   = (const float*)d_in[11];
    const float* beta    = (const float*)d_in[12];

    char* ws = (char*)d_ws;
    size_t off = 0;
    auto alloc = [&](size_t bytes) -> char* {
        char* p = ws + off;
        off += (bytes + 255) & ~(size_t)255;
        return p;
    };
    u16* WVh     = (u16*)alloc((size_t)NN * 512 * 2);     // Wh | Vh interleaved per node
    u16* wT      = (u16*)alloc((size_t)768 * 256 * 2);
    int* deg     = (int*)alloc((size_t)NN * 4);
    int* rows    = (int*)alloc((size_t)(NN + 1) * 4);
    int* cursor  = (int*)alloc((size_t)NN * 4);
    int* esrc    = (int*)alloc((size_t)NE * 4);
    int* bsum    = (int*)alloc((size_t)NB * 4);
    int* bpre    = (int*)alloc((size_t)NB * 4);

    float* Uh_f32 = (float*)d_out;   // staged in d_out, overwritten by node_kernel

    hipMemsetAsync(deg, 0, (size_t)NN * 4, stream);

    tw_kernel<<<dim3(8, 8, 3), 256, 0, stream>>>(W_w, U_w, V_w, wT);
    hist_kernel<<<(NE + 255) / 256, 256, 0, stream>>>(dst, deg);
    scanA_kernel<<<NB, 256, 0, stream>>>(deg, bsum);
    scanB_kernel<<<1, 256, 0, stream>>>(bsum, bpre, rows + NN);
    scanC_kernel<<<NB, 256, 0, stream>>>(deg, bpre, rows, cursor);
    scatter_kernel<<<(NE + 255) / 256, 256, 0, stream>>>(src, dst, cursor, esrc);

    dim3 gg((NN + 127) / 128, 6);
    gemm_kernel<<<gg, 256, 0, stream>>>(x, wT, W_b, U_b, V_b, WVh, Uh_f32);

    node_kernel<<<(NN + 3) / 4, 256, 0, stream>>>(
        WVh, x, rows, esrc, attn_l, attn_r, gamma, beta, (float*)d_out);
}

// Round 4
// 300.008 us; speedup vs baseline: 1.5451x; 1.1308x over previous
//
#include <hip/hip_runtime.h>
#include <hip/hip_bf16.h>

#define NN 50000
#define NE 800000
#define NB 196          // ceil(NN/256)
#define NROWPAD 50048   // 128-row padded for global_load_lds OOB safety

typedef __attribute__((ext_vector_type(8))) short short8;
typedef __attribute__((ext_vector_type(4))) float floatx4;
typedef unsigned short u16;
typedef unsigned int u32;

__device__ __forceinline__ u16 f2bf(float f) {
    u32 u = __float_as_uint(f);
    u += 0x7FFFu + ((u >> 16) & 1u);   // RNE
    return (u16)(u >> 16);
}
__device__ __forceinline__ float bf_lo(u32 u) { return __uint_as_float(u << 16); }
__device__ __forceinline__ float bf_hi(u32 u) { return __uint_as_float(u & 0xFFFF0000u); }
__device__ __forceinline__ u32 pack_bf(float lo, float hi) {
    return (u32)f2bf(lo) | ((u32)f2bf(hi) << 16);
}
__device__ __forceinline__ void gl_lds16(const void* g, void* l) {
    __builtin_amdgcn_global_load_lds((const __attribute__((address_space(1))) void*)g,
                                     (__attribute__((address_space(3))) void*)l, 16, 0, 0);
}

// ---------------- x (fp32) -> xbf (bf16), 8 elems/thread ----------------
__global__ __launch_bounds__(256) void xcvt_kernel(const float* __restrict__ x, u16* __restrict__ xbf) {
    size_t i = (size_t)(blockIdx.x * 256 + threadIdx.x) * 8;
    floatx4 f0 = *(const floatx4*)(x + i);
    floatx4 f1 = *(const floatx4*)(x + i + 4);
    uint4 pk;
    pk.x = pack_bf(f0[0], f0[1]);
    pk.y = pack_bf(f0[2], f0[3]);
    pk.z = pack_bf(f1[0], f1[1]);
    pk.w = pack_bf(f1[2], f1[3]);
    *(uint4*)(xbf + i) = pk;
}

// ---------------- W/U/V transpose + bf16: wT[g*256 + j][k] = M_g[k][j] ----------------
__global__ __launch_bounds__(256) void tw_kernel(const float* __restrict__ W, const float* __restrict__ U,
                                                 const float* __restrict__ V, u16* __restrict__ wT) {
    __shared__ float s[32][33];
    int g = blockIdx.z;
    const float* M = (g == 0) ? W : ((g == 1) ? U : V);
    int r0 = blockIdx.x * 32, c0 = blockIdx.y * 32;
    int tx = threadIdx.x & 31, ty = threadIdx.x >> 5;   // 32 x 8
#pragma unroll
    for (int k = 0; k < 4; ++k)
        s[ty + k * 8][tx] = M[(size_t)(r0 + ty + k * 8) * 256 + c0 + tx];
    __syncthreads();
#pragma unroll
    for (int k = 0; k < 4; ++k)
        wT[(size_t)(g * 256 + c0 + ty + k * 8) * 256 + r0 + tx] = f2bf(s[tx][ty + k * 8]);
}

// ---------------- degree histogram ----------------
__global__ void hist_kernel(const int* __restrict__ dst, int* __restrict__ deg) {
    int e = blockIdx.x * 256 + threadIdx.x;
    if (e < NE) atomicAdd(&deg[dst[e]], 1);
}

// ---------------- 3-phase scan ----------------
__global__ __launch_bounds__(256) void scanA_kernel(const int* __restrict__ deg, int* __restrict__ bsum) {
    int t = threadIdx.x;
    int i = blockIdx.x * 256 + t;
    int v = (i < NN) ? deg[i] : 0;
#pragma unroll
    for (int m = 32; m; m >>= 1) v += __shfl_xor(v, m, 64);
    __shared__ int ws[4];
    if ((t & 63) == 0) ws[t >> 6] = v;
    __syncthreads();
    if (t == 0) bsum[blockIdx.x] = ws[0] + ws[1] + ws[2] + ws[3];
}

__global__ __launch_bounds__(256) void scanB_kernel(const int* __restrict__ bsum, int* __restrict__ bpre,
                                                    int* __restrict__ rows_end) {
    int t = threadIdx.x, lane = t & 63, wv = t >> 6;
    int v = (t < NB) ? bsum[t] : 0;
    int inc = v;
#pragma unroll
    for (int off = 1; off < 64; off <<= 1) {
        int u = __shfl_up(inc, off, 64);
        if (lane >= off) inc += u;
    }
    __shared__ int wsum[4];
    if (lane == 63) wsum[wv] = inc;
    __syncthreads();
    int woff = 0;
    for (int k = 0; k < wv; ++k) woff += wsum[k];
    if (t < NB) bpre[t] = woff + inc - v;
    if (t == 255) rows_end[0] = woff + inc;
}

__global__ __launch_bounds__(256) void scanC_kernel(const int* __restrict__ deg, const int* __restrict__ bpre,
                                                    int* __restrict__ rows, int* __restrict__ cursor) {
    int t = threadIdx.x, lane = t & 63, wv = t >> 6;
    int i = blockIdx.x * 256 + t;
    int v = (i < NN) ? deg[i] : 0;
    int inc = v;
#pragma unroll
    for (int off = 1; off < 64; off <<= 1) {
        int u = __shfl_up(inc, off, 64);
        if (lane >= off) inc += u;
    }
    __shared__ int wsum[4];
    if (lane == 63) wsum[wv] = inc;
    __syncthreads();
    int woff = bpre[blockIdx.x];
    for (int k = 0; k < wv; ++k) woff += wsum[k];
    int excl = woff + inc - v;
    if (i < NN) { rows[i] = excl; cursor[i] = excl; }
}

// ---------------- scatter edges into CSR-by-dst ----------------
__global__ void scatter_kernel(const int* __restrict__ src, const int* __restrict__ dst,
                               int* __restrict__ cursor, int* __restrict__ esrc) {
    int e = blockIdx.x * 256 + threadIdx.x;
    if (e < NE) {
        int d = dst[e];
        int pos = atomicAdd(&cursor[d], 1);
        esrc[pos] = src[e];
    }
}

// ===================== GEMM (bf16 A path): [N,256] x [256,768], 128x128 tile, BK=64 ==========
// A and B both staged via global_load_lds(16B) with pre-swizzled source quads.
__global__ __launch_bounds__(256) void gemm_bf_kernel(
    const u16* __restrict__ xbf, const u16* __restrict__ wT,
    const float* __restrict__ Wb, const float* __restrict__ Ub, const float* __restrict__ Vb,
    u16* __restrict__ WVh, float* __restrict__ Uh) {
    __shared__ __align__(16) u16 As[128 * 64];
    __shared__ __align__(16) u16 Bs[128 * 64];

    int rb = blockIdx.x * 128;
    int cbg = blockIdx.y * 128;
    int t = threadIdx.x, lane = t & 63, w = t >> 6;
    int wm = w >> 1, wn = w & 1;

    floatx4 acc[4][4] = {};

    int subrow = lane >> 3;               // 0..7
    int qv = lane & 7;                    // 16B quad

    for (int kt = 0; kt < 4; ++kt) {
        int k0 = kt * 64;
#pragma unroll
        for (int ii = 0; ii < 4; ++ii) {
            int rowbase = (w * 4 + ii) * 8;
            int row = rowbase + subrow;
            int qa = qv ^ (row & 7);
            gl_lds16(wT + (size_t)(cbg + row) * 256 + k0 + qa * 8, Bs + rowbase * 64);
            gl_lds16(xbf + (size_t)(rb + row) * 256 + k0 + qa * 8, As + rowbase * 64);
        }
        __syncthreads();

#pragma unroll
        for (int s = 0; s < 2; ++s) {
            short8 a[4], b[4];
#pragma unroll
            for (int i = 0; i < 4; ++i) {
                int ar = wm * 64 + i * 16 + (lane & 15);
                int q = s * 4 + (lane >> 4);
                a[i] = *(const short8*)(As + ar * 64 + ((q ^ (ar & 7)) * 8));
                int br = wn * 64 + i * 16 + (lane & 15);
                b[i] = *(const short8*)(Bs + br * 64 + ((q ^ (br & 7)) * 8));
            }
#pragma unroll
            for (int i = 0; i < 4; ++i)
#pragma unroll
                for (int j = 0; j < 4; ++j)
                    acc[i][j] = __builtin_amdgcn_mfma_f32_16x16x32_bf16(a[i], b[j], acc[i][j], 0, 0, 0);
        }
        __syncthreads();
    }

    int g = cbg >> 8;
    int cloc = cbg & 255;
    const float* bias = (g == 0) ? Wb : ((g == 1) ? Ub : Vb);
#pragma unroll
    for (int i = 0; i < 4; ++i)
#pragma unroll
        for (int j = 0; j < 4; ++j) {
            int col = cloc + wn * 64 + j * 16 + (lane & 15);
            float bv = bias[col];
#pragma unroll
            for (int r = 0; r < 4; ++r) {
                int row = rb + wm * 64 + i * 16 + (lane >> 4) * 4 + r;
                if (row < NN) {
                    float val = acc[i][j][r] + bv;
                    if (g == 0)      WVh[(size_t)row * 512 + col] = f2bf(val);
                    else if (g == 1) Uh[(size_t)row * 256 + col] = val;
                    else             WVh[(size_t)row * 512 + 256 + col] = f2bf(val);
                }
            }
        }
}

// ===================== GEMM fallback (fp32 A, pack in kernel) — round-3 proven ==========
__global__ __launch_bounds__(256) void gemm_f32_kernel(
    const float* __restrict__ x, const u16* __restrict__ wT,
    const float* __restrict__ Wb, const float* __restrict__ Ub, const float* __restrict__ Vb,
    u16* __restrict__ WVh, float* __restrict__ Uh) {
    __shared__ __align__(16) u16 As[128 * 64];
    __shared__ __align__(16) u16 Bs[128 * 64];

    int rb = blockIdx.x * 128;
    int cbg = blockIdx.y * 128;
    int t = threadIdx.x, lane = t & 63, w = t >> 6;
    int wm = w >> 1, wn = w & 1;

    floatx4 acc[4][4] = {};
    int b_subrow = lane >> 3;
    int b_q = lane & 7;
    int a_row = t >> 1;
    int a_half = t & 1;

    for (int kt = 0; kt < 4; ++kt) {
        int k0 = kt * 64;
#pragma unroll
        for (int ii = 0; ii < 4; ++ii) {
            int rowbase = (w * 4 + ii) * 8;
            int row = rowbase + b_subrow;
            int qa = b_q ^ (row & 7);
            gl_lds16(wT + (size_t)(cbg + row) * 256 + k0 + qa * 8, Bs + rowbase * 64);
        }
        int grow = rb + a_row;
        uint4 pk[4] = {};
        if (grow < NN) {
            const float* px = x + (size_t)grow * 256 + k0 + a_half * 32;
#pragma unroll
            for (int c = 0; c < 4; ++c) {
                floatx4 f0 = *(const floatx4*)(px + c * 8);
                floatx4 f1 = *(const floatx4*)(px + c * 8 + 4);
                pk[c].x = pack_bf(f0[0], f0[1]);
                pk[c].y = pack_bf(f0[2], f0[3]);
                pk[c].z = pack_bf(f1[0], f1[1]);
                pk[c].w = pack_bf(f1[2], f1[3]);
            }
        }
#pragma unroll
        for (int c = 0; c < 4; ++c) {
            int q = a_half * 4 + c;
            *(uint4*)(As + a_row * 64 + ((q ^ (a_row & 7)) * 8)) = pk[c];
        }
        __syncthreads();

#pragma unroll
        for (int s = 0; s < 2; ++s) {
            short8 a[4], b[4];
#pragma unroll
            for (int i = 0; i < 4; ++i) {
                int ar = wm * 64 + i * 16 + (lane & 15);
                int q = s * 4 + (lane >> 4);
                a[i] = *(const short8*)(As + ar * 64 + ((q ^ (ar & 7)) * 8));
                int br = wn * 64 + i * 16 + (lane & 15);
                b[i] = *(const short8*)(Bs + br * 64 + ((q ^ (br & 7)) * 8));
            }
#pragma unroll
            for (int i = 0; i < 4; ++i)
#pragma unroll
                for (int j = 0; j < 4; ++j)
                    acc[i][j] = __builtin_amdgcn_mfma_f32_16x16x32_bf16(a[i], b[j], acc[i][j], 0, 0, 0);
        }
        __syncthreads();
    }

    int g = cbg >> 8;
    int cloc = cbg & 255;
    const float* bias = (g == 0) ? Wb : ((g == 1) ? Ub : Vb);
#pragma unroll
    for (int i = 0; i < 4; ++i)
#pragma unroll
        for (int j = 0; j < 4; ++j) {
            int col = cloc + wn * 64 + j * 16 + (lane & 15);
            float bv = bias[col];
#pragma unroll
            for (int r = 0; r < 4; ++r) {
                int row = rb + wm * 64 + i * 16 + (lane >> 4) * 4 + r;
                if (row < NN) {
                    float val = acc[i][j][r] + bv;
                    if (g == 0)      WVh[(size_t)row * 512 + col] = f2bf(val);
                    else if (g == 1) Uh[(size_t)row * 256 + col] = val;
                    else             WVh[(size_t)row * 512 + 256 + col] = f2bf(val);
                }
            }
        }
}

// ---------------- node-centric aggregate + LN + ReLU + residual ----------------
__global__ __launch_bounds__(256) void node_kernel(
    const u16* __restrict__ WVh, const float* __restrict__ x,
    const int* __restrict__ rows, const int* __restrict__ esrc,
    const float* __restrict__ attn_l, const float* __restrict__ attn_r,
    const float* __restrict__ gamma, const float* __restrict__ beta,
    float* inout) {
    int wv = threadIdx.x >> 6, lane = threadIdx.x & 63;
    int v = blockIdx.x * 4 + wv;
    if (v >= NN) return;
    int c0 = lane * 4;

    floatx4 alv = *(const floatx4*)(attn_l + c0);
    floatx4 arv = *(const floatx4*)(attn_r + c0);
    uint2 wvv = *(const uint2*)(WVh + (size_t)v * 512 + c0);
    // arg of sigmoid: tt = wf*al + td ;  we compute m = -tt = wf*al2 + td2
    float al2[4] = { -alv[0], -alv[1], -alv[2], -alv[3] };
    float td2[4] = { -bf_lo(wvv.x) * arv[0], -bf_hi(wvv.x) * arv[1],
                     -bf_lo(wvv.y) * arv[2], -bf_hi(wvv.y) * arv[3] };

    float acc_h[4] = {0.f, 0.f, 0.f, 0.f};
    float acc_s[4] = {0.f, 0.f, 0.f, 0.f};

    auto edge = [&](uint2 wu, uint2 vu) {
        float wf[4] = { bf_lo(wu.x), bf_hi(wu.x), bf_lo(wu.y), bf_hi(wu.y) };
        float vf[4] = { bf_lo(vu.x), bf_hi(vu.x), bf_lo(vu.y), bf_hi(vu.y) };
#pragma unroll
        for (int j = 0; j < 4; ++j) {
            float m = fmaf(wf[j], al2[j], td2[j]);
            float s = __builtin_amdgcn_rcpf(1.0f + __expf(m));
            acc_s[j] += s;
            acc_h[j] = fmaf(s, vf[j], acc_h[j]);
        }
    };

    int e = rows[v], e1 = rows[v + 1];
    for (; e + 4 <= e1; e += 4) {
        int ua = esrc[e], ub = esrc[e + 1], uc = esrc[e + 2], ud = esrc[e + 3];
        const u16* pa = WVh + (size_t)ua * 512 + c0;
        const u16* pb = WVh + (size_t)ub * 512 + c0;
        const u16* pc = WVh + (size_t)uc * 512 + c0;
        const u16* pd = WVh + (size_t)ud * 512 + c0;
        uint2 wa = *(const uint2*)pa, va = *(const uint2*)(pa + 256);
        uint2 wb = *(const uint2*)pb, vb = *(const uint2*)(pb + 256);
        uint2 wc = *(const uint2*)pc, vc = *(const uint2*)(pc + 256);
        uint2 wd = *(const uint2*)pd, vd = *(const uint2*)(pd + 256);
        edge(wa, va); edge(wb, vb); edge(wc, vc); edge(wd, vd);
    }
    for (; e < e1; ++e) {
        int u = esrc[e];
        const u16* p = WVh + (size_t)u * 512 + c0;
        uint2 wu = *(const uint2*)p, vu = *(const uint2*)(p + 256);
        edge(wu, vu);
    }

    floatx4 uh = *(const floatx4*)(inout + (size_t)v * 256 + c0);
    float h[4];
#pragma unroll
    for (int j = 0; j < 4; ++j)
        h[j] = uh[j] + acc_h[j] * __builtin_amdgcn_rcpf(acc_s[j] + 1e-6f);

    float s01 = h[0] + h[1] + h[2] + h[3];
#pragma unroll
    for (int m = 32; m; m >>= 1) s01 += __shfl_xor(s01, m, 64);
    float mu = s01 * (1.0f / 256.0f);
    float d[4] = { h[0] - mu, h[1] - mu, h[2] - mu, h[3] - mu };
    float sq = d[0] * d[0] + d[1] * d[1] + d[2] * d[2] + d[3] * d[3];
#pragma unroll
    for (int m = 32; m; m >>= 1) sq += __shfl_xor(sq, m, 64);
    float inv = rsqrtf(sq * (1.0f / 256.0f) + 1e-6f);

    floatx4 gm = *(const floatx4*)(gamma + c0);
    floatx4 bt = *(const floatx4*)(beta + c0);
    floatx4 xr = *(const floatx4*)(x + (size_t)v * 256 + c0);
    floatx4 res;
#pragma unroll
    for (int j = 0; j < 4; ++j) {
        float y = d[j] * inv * gm[j] + bt[j];
        y = fmaxf(y, 0.0f);
        res[j] = xr[j] + y;
    }
    *(floatx4*)(inout + (size_t)v * 256 + c0) = res;
}

extern "C" void kernel_launch(void* const* d_in, const int* in_sizes, int n_in,
                              void* d_out, int out_size, void* d_ws, size_t ws_size,
                              hipStream_t stream) {
    const float* x       = (const float*)d_in[0];
    const int*   src     = (const int*)d_in[1];
    const int*   dst     = (const int*)d_in[2];
    const float* W_w     = (const float*)d_in[3];
    const float* W_b     = (const float*)d_in[4];
    const float* U_w     = (const float*)d_in[5];
    const float* U_b     = (const float*)d_in[6];
    const float* V_w     = (const float*)d_in[7];
    const float* V_b     = (const float*)d_in[8];
    const float* attn_l  = (const float*)d_in[9];
    const float* attn_r  = (const float*)d_in[10];
    const float* gamma   = (const float*)d_in[11];
    const float* beta    = (const float*)d_in[12];

    char* ws = (char*)d_ws;
    size_t off = 0;
    auto alloc = [&](size_t bytes) -> char* {
        char* p = ws + off;
        off += (bytes + 255) & ~(size_t)255;
        return p;
    };
    u16* WVh     = (u16*)alloc((size_t)NN * 512 * 2);     // Wh | Vh interleaved per node
    u16* wT      = (u16*)alloc((size_t)768 * 256 * 2);
    int* deg     = (int*)alloc((size_t)NN * 4);
    int* rows    = (int*)alloc((size_t)(NN + 1) * 4);
    int* cursor  = (int*)alloc((size_t)NN * 4);
    int* esrc    = (int*)alloc((size_t)NE * 4);
    int* bsum    = (int*)alloc((size_t)NB * 4);
    int* bpre    = (int*)alloc((size_t)NB * 4);
    u16* xbf     = (u16*)alloc((size_t)NROWPAD * 256 * 2);   // optional (last)
    bool use_bf  = (ws_size >= off);

    float* Uh_f32 = (float*)d_out;   // staged in d_out, overwritten by node_kernel

    hipMemsetAsync(deg, 0, (size_t)NN * 4, stream);

    tw_kernel<<<dim3(8, 8, 3), 256, 0, stream>>>(W_w, U_w, V_w, wT);
    hist_kernel<<<(NE + 255) / 256, 256, 0, stream>>>(dst, deg);
    scanA_kernel<<<NB, 256, 0, stream>>>(deg, bsum);
    scanB_kernel<<<1, 256, 0, stream>>>(bsum, bpre, rows + NN);
    scanC_kernel<<<NB, 256, 0, stream>>>(deg, bpre, rows, cursor);
    scatter_kernel<<<(NE + 255) / 256, 256, 0, stream>>>(src, dst, cursor, esrc);

    dim3 gg((NN + 127) / 128, 6);
    if (use_bf) {
        xcvt_kernel<<<(NN * 256 / 8 + 255) / 256, 256, 0, stream>>>(x, xbf);
        gemm_bf_kernel<<<gg, 256, 0, stream>>>(xbf, wT, W_b, U_b, V_b, WVh, Uh_f32);
    } else {
        gemm_f32_kernel<<<gg, 256, 0, stream>>>(x, wT, W_b, U_b, V_b, WVh, Uh_f32);
    }

    node_kernel<<<(NN + 3) / 4, 256, 0, stream>>>(
        WVh, x, rows, esrc, attn_l, attn_r, gamma, beta, (float*)d_out);
}

// Round 5
// 295.389 us; speedup vs baseline: 1.5693x; 1.0156x over previous
//
#include <hip/hip_runtime.h>
#include <hip/hip_bf16.h>

#define NN 50000
#define NE 800000
#define NB 196          // ceil(NN/256)
#define NROWPAD 50048   // 128-row padded so GEMM A-tile reads stay in-bounds

#define XCVT_BLOCKS 6250    // NN*256/8/256
#define TW_BLOCKS   192     // 8*8*3
#define HIST_BLOCKS 3125    // ceil(NE/256)
#define SCAT_BLOCKS 3125
#define GEMM_BLOCKS (391*3) // 391 row-blocks x 3 col-groups

typedef __attribute__((ext_vector_type(8))) short short8;
typedef __attribute__((ext_vector_type(4))) float floatx4;
typedef unsigned short u16;
typedef unsigned int u32;

__device__ __forceinline__ u16 f2bf(float f) {
    u32 u = __float_as_uint(f);
    u += 0x7FFFu + ((u >> 16) & 1u);   // RNE
    return (u16)(u >> 16);
}
__device__ __forceinline__ float bf_lo(u32 u) { return __uint_as_float(u << 16); }
__device__ __forceinline__ float bf_hi(u32 u) { return __uint_as_float(u & 0xFFFF0000u); }
__device__ __forceinline__ u32 pack_bf(float lo, float hi) {
    return (u32)f2bf(lo) | ((u32)f2bf(hi) << 16);
}
__device__ __forceinline__ void gl_lds16(const void* g, void* l) {
    __builtin_amdgcn_global_load_lds((const __attribute__((address_space(1))) void*)g,
                                     (__attribute__((address_space(3))) void*)l, 16, 0, 0);
}

#if __has_builtin(__builtin_amdgcn_exp2f)
#define EXP2F(x) __builtin_amdgcn_exp2f(x)
#else
#define EXP2F(x) exp2f(x)
#endif

// =============== prep: xcvt (x->bf16) + W/U/V transpose + degree histogram ===============
__global__ __launch_bounds__(256) void prep_kernel(
    const float* __restrict__ x, u16* __restrict__ xbf,
    const float* __restrict__ W, const float* __restrict__ U, const float* __restrict__ V,
    u16* __restrict__ wT, const int* __restrict__ dst, int* __restrict__ deg) {
    __shared__ float s[32][33];
    int b = blockIdx.x;
    if (b < XCVT_BLOCKS) {
        size_t i = ((size_t)b * 256 + threadIdx.x) * 8;
        floatx4 f0 = *(const floatx4*)(x + i);
        floatx4 f1 = *(const floatx4*)(x + i + 4);
        uint4 pk;
        pk.x = pack_bf(f0[0], f0[1]);
        pk.y = pack_bf(f0[2], f0[3]);
        pk.z = pack_bf(f1[0], f1[1]);
        pk.w = pack_bf(f1[2], f1[3]);
        *(uint4*)(xbf + i) = pk;
    } else if (b < XCVT_BLOCKS + TW_BLOCKS) {
        int bb = b - XCVT_BLOCKS;
        int g = bb >> 6, rem = bb & 63;
        int r0 = (rem & 7) * 32, c0 = (rem >> 3) * 32;
        const float* M = (g == 0) ? W : ((g == 1) ? U : V);
        int tx = threadIdx.x & 31, ty = threadIdx.x >> 5;   // 32 x 8
#pragma unroll
        for (int k = 0; k < 4; ++k)
            s[ty + k * 8][tx] = M[(size_t)(r0 + ty + k * 8) * 256 + c0 + tx];
        __syncthreads();
#pragma unroll
        for (int k = 0; k < 4; ++k)
            wT[(size_t)(g * 256 + c0 + ty + k * 8) * 256 + r0 + tx] = f2bf(s[tx][ty + k * 8]);
    } else {
        int e = (b - XCVT_BLOCKS - TW_BLOCKS) * 256 + threadIdx.x;
        if (e < NE) atomicAdd(&deg[dst[e]], 1);
    }
}

// ---------------- 3-phase scan ----------------
__global__ __launch_bounds__(256) void scanA_kernel(const int* __restrict__ deg, int* __restrict__ bsum) {
    int t = threadIdx.x;
    int i = blockIdx.x * 256 + t;
    int v = (i < NN) ? deg[i] : 0;
#pragma unroll
    for (int m = 32; m; m >>= 1) v += __shfl_xor(v, m, 64);
    __shared__ int ws[4];
    if ((t & 63) == 0) ws[t >> 6] = v;
    __syncthreads();
    if (t == 0) bsum[blockIdx.x] = ws[0] + ws[1] + ws[2] + ws[3];
}

__global__ __launch_bounds__(256) void scanB_kernel(const int* __restrict__ bsum, int* __restrict__ bpre,
                                                    int* __restrict__ rows_end) {
    int t = threadIdx.x, lane = t & 63, wv = t >> 6;
    int v = (t < NB) ? bsum[t] : 0;
    int inc = v;
#pragma unroll
    for (int off = 1; off < 64; off <<= 1) {
        int u = __shfl_up(inc, off, 64);
        if (lane >= off) inc += u;
    }
    __shared__ int wsum[4];
    if (lane == 63) wsum[wv] = inc;
    __syncthreads();
    int woff = 0;
    for (int k = 0; k < wv; ++k) woff += wsum[k];
    if (t < NB) bpre[t] = woff + inc - v;
    if (t == 255) rows_end[0] = woff + inc;
}

__global__ __launch_bounds__(256) void scanC_kernel(const int* __restrict__ deg, const int* __restrict__ bpre,
                                                    int* __restrict__ rows, int* __restrict__ cursor) {
    int t = threadIdx.x, lane = t & 63, wv = t >> 6;
    int i = blockIdx.x * 256 + t;
    int v = (i < NN) ? deg[i] : 0;
    int inc = v;
#pragma unroll
    for (int off = 1; off < 64; off <<= 1) {
        int u = __shfl_up(inc, off, 64);
        if (lane >= off) inc += u;
    }
    __shared__ int wsum[4];
    if (lane == 63) wsum[wv] = inc;
    __syncthreads();
    int woff = bpre[blockIdx.x];
    for (int k = 0; k < wv; ++k) woff += wsum[k];
    int excl = woff + inc - v;
    if (i < NN) { rows[i] = excl; cursor[i] = excl; }
}

// =============== fused: scatter (first) + GEMM 128x256 tiles ===============
// GEMM: [N,256] x [256,768]; col-group g in {0,1,2} selects W/U/V.
// A staged from xbf (bf16) via global_load_lds, or packed from fp32 x (fallback).
template<bool USE_BF>
__global__ __launch_bounds__(256, 2) void gemmsc_kernel(
    const u16* __restrict__ xbf, const float* __restrict__ xf, const u16* __restrict__ wT,
    const float* __restrict__ Wb, const float* __restrict__ Ub, const float* __restrict__ Vb,
    u16* __restrict__ WVh, float* __restrict__ Uh,
    const int* __restrict__ src, const int* __restrict__ dst,
    int* __restrict__ cursor, int* __restrict__ esrc) {
    __shared__ __align__(16) u16 As[128 * 64];
    __shared__ __align__(16) u16 Bs[2][128 * 64];

    int b = blockIdx.x;
    if (b < SCAT_BLOCKS) {
        int e = b * 256 + threadIdx.x;
        if (e < NE) {
            int d = dst[e];
            int pos = atomicAdd(&cursor[d], 1);
            esrc[pos] = src[e];
        }
        return;
    }
    int gb = b - SCAT_BLOCKS;
    int rb = (gb % 391) * 128;
    int cgy = gb / 391;                 // 0..2 -> W,U,V
    int cbg = cgy * 256;

    int t = threadIdx.x, lane = t & 63, w = t >> 6;
    int wm = w >> 1, wn = w & 1;

    floatx4 acc[2][4][4] = {};

    int subrow = lane >> 3;             // 0..7
    int qv = lane & 7;                  // 16B quad
    int a_row = t >> 1;                 // fallback pack geometry
    int a_half = t & 1;

    for (int kt = 0; kt < 4; ++kt) {
        int k0 = kt * 64;
#pragma unroll
        for (int ii = 0; ii < 4; ++ii) {
            int rowbase = (w * 4 + ii) * 8;
            int row = rowbase + subrow;
            int qa = qv ^ (row & 7);
            gl_lds16(wT + (size_t)(cbg + row) * 256 + k0 + qa * 8, Bs[0] + rowbase * 64);
            gl_lds16(wT + (size_t)(cbg + 128 + row) * 256 + k0 + qa * 8, Bs[1] + rowbase * 64);
            if (USE_BF)
                gl_lds16(xbf + (size_t)(rb + row) * 256 + k0 + qa * 8, As + rowbase * 64);
        }
        if (!USE_BF) {
            int grow = rb + a_row;
            uint4 pk[4] = {};
            if (grow < NN) {
                const float* px = xf + (size_t)grow * 256 + k0 + a_half * 32;
#pragma unroll
                for (int c = 0; c < 4; ++c) {
                    floatx4 f0 = *(const floatx4*)(px + c * 8);
                    floatx4 f1 = *(const floatx4*)(px + c * 8 + 4);
                    pk[c].x = pack_bf(f0[0], f0[1]);
                    pk[c].y = pack_bf(f0[2], f0[3]);
                    pk[c].z = pack_bf(f1[0], f1[1]);
                    pk[c].w = pack_bf(f1[2], f1[3]);
                }
            }
#pragma unroll
            for (int c = 0; c < 4; ++c) {
                int q = a_half * 4 + c;
                *(uint4*)(As + a_row * 64 + ((q ^ (a_row & 7)) * 8)) = pk[c];
            }
        }
        __syncthreads();

#pragma unroll
        for (int s = 0; s < 2; ++s) {
            short8 a[4], bfr[2][4];
            int q = s * 4 + (lane >> 4);
#pragma unroll
            for (int i = 0; i < 4; ++i) {
                int ar = wm * 64 + i * 16 + (lane & 15);
                a[i] = *(const short8*)(As + ar * 64 + ((q ^ (ar & 7)) * 8));
            }
#pragma unroll
            for (int ch = 0; ch < 2; ++ch)
#pragma unroll
                for (int j = 0; j < 4; ++j) {
                    int br = wn * 64 + j * 16 + (lane & 15);
                    bfr[ch][j] = *(const short8*)(Bs[ch] + br * 64 + ((q ^ (br & 7)) * 8));
                }
#pragma unroll
            for (int ch = 0; ch < 2; ++ch)
#pragma unroll
                for (int i = 0; i < 4; ++i)
#pragma unroll
                    for (int j = 0; j < 4; ++j)
                        acc[ch][i][j] = __builtin_amdgcn_mfma_f32_16x16x32_bf16(
                            a[i], bfr[ch][j], acc[ch][i][j], 0, 0, 0);
        }
        __syncthreads();
    }

    const float* bias = (cgy == 0) ? Wb : ((cgy == 1) ? Ub : Vb);
#pragma unroll
    for (int ch = 0; ch < 2; ++ch)
#pragma unroll
        for (int i = 0; i < 4; ++i)
#pragma unroll
            for (int j = 0; j < 4; ++j) {
                int col = ch * 128 + wn * 64 + j * 16 + (lane & 15);
                float bv = bias[col];
#pragma unroll
                for (int r = 0; r < 4; ++r) {
                    int row = rb + wm * 64 + i * 16 + (lane >> 4) * 4 + r;
                    if (row < NN) {
                        float val = acc[ch][i][j][r] + bv;
                        if (cgy == 0)      WVh[(size_t)row * 512 + col] = f2bf(val);
                        else if (cgy == 1) Uh[(size_t)row * 256 + col] = val;
                        else               WVh[(size_t)row * 512 + 256 + col] = f2bf(val);
                    }
                }
            }
}

// ---------------- node-centric aggregate + LN + ReLU + residual ----------------
__global__ __launch_bounds__(256) void node_kernel(
    const u16* __restrict__ WVh, const float* __restrict__ x,
    const int* __restrict__ rows, const int* __restrict__ esrc,
    const float* __restrict__ attn_l, const float* __restrict__ attn_r,
    const float* __restrict__ gamma, const float* __restrict__ beta,
    float* inout) {
    int wv = threadIdx.x >> 6, lane = threadIdx.x & 63;
    int v = blockIdx.x * 4 + wv;
    if (v >= NN) return;
    int c0 = lane * 4;

    const float NL2E = -1.44269504f;    // -log2(e)
    floatx4 alv = *(const floatx4*)(attn_l + c0);
    floatx4 arv = *(const floatx4*)(attn_r + c0);
    uint2 wvv = *(const uint2*)(WVh + (size_t)v * 512 + c0);
    // sigmoid(t) = 1/(1+exp2(t * -log2e));  t = wf*al + td
    float al2[4] = { alv[0] * NL2E, alv[1] * NL2E, alv[2] * NL2E, alv[3] * NL2E };
    float td2[4] = { bf_lo(wvv.x) * arv[0] * NL2E, bf_hi(wvv.x) * arv[1] * NL2E,
                     bf_lo(wvv.y) * arv[2] * NL2E, bf_hi(wvv.y) * arv[3] * NL2E };

    float acc_h[4] = {0.f, 0.f, 0.f, 0.f};
    float acc_s[4] = {0.f, 0.f, 0.f, 0.f};

    auto edge = [&](uint2 wu, uint2 vu) {
        float wf[4] = { bf_lo(wu.x), bf_hi(wu.x), bf_lo(wu.y), bf_hi(wu.y) };
        float vf[4] = { bf_lo(vu.x), bf_hi(vu.x), bf_lo(vu.y), bf_hi(vu.y) };
#pragma unroll
        for (int j = 0; j < 4; ++j) {
            float m = fmaf(wf[j], al2[j], td2[j]);
            float s = __builtin_amdgcn_rcpf(1.0f + EXP2F(m));
            acc_s[j] += s;
            acc_h[j] = fmaf(s, vf[j], acc_h[j]);
        }
    };

    int e = rows[v], e1 = rows[v + 1];
    for (; e + 8 <= e1; e += 8) {
        int us[8];
#pragma unroll
        for (int q = 0; q < 8; ++q) us[q] = esrc[e + q];
        uint2 wu[8], vu[8];
#pragma unroll
        for (int q = 0; q < 8; ++q) {
            const u16* p = WVh + (size_t)us[q] * 512 + c0;
            wu[q] = *(const uint2*)p;
            vu[q] = *(const uint2*)(p + 256);
        }
#pragma unroll
        for (int q = 0; q < 8; ++q) edge(wu[q], vu[q]);
    }
    for (; e + 2 <= e1; e += 2) {
        int ua = esrc[e], ub = esrc[e + 1];
        const u16* pa = WVh + (size_t)ua * 512 + c0;
        const u16* pb = WVh + (size_t)ub * 512 + c0;
        uint2 wa = *(const uint2*)pa, va = *(const uint2*)(pa + 256);
        uint2 wb = *(const uint2*)pb, vb = *(const uint2*)(pb + 256);
        edge(wa, va); edge(wb, vb);
    }
    for (; e < e1; ++e) {
        int u = esrc[e];
        const u16* p = WVh + (size_t)u * 512 + c0;
        uint2 wu = *(const uint2*)p, vu = *(const uint2*)(p + 256);
        edge(wu, vu);
    }

    floatx4 uh = *(const floatx4*)(inout + (size_t)v * 256 + c0);
    float h[4];
#pragma unroll
    for (int j = 0; j < 4; ++j)
        h[j] = uh[j] + acc_h[j] * __builtin_amdgcn_rcpf(acc_s[j] + 1e-6f);

    float s01 = h[0] + h[1] + h[2] + h[3];
#pragma unroll
    for (int m = 32; m; m >>= 1) s01 += __shfl_xor(s01, m, 64);
    float mu = s01 * (1.0f / 256.0f);
    float d[4] = { h[0] - mu, h[1] - mu, h[2] - mu, h[3] - mu };
    float sq = d[0] * d[0] + d[1] * d[1] + d[2] * d[2] + d[3] * d[3];
#pragma unroll
    for (int m = 32; m; m >>= 1) sq += __shfl_xor(sq, m, 64);
    float inv = rsqrtf(sq * (1.0f / 256.0f) + 1e-6f);

    floatx4 gm = *(const floatx4*)(gamma + c0);
    floatx4 bt = *(const floatx4*)(beta + c0);
    floatx4 xr = *(const floatx4*)(x + (size_t)v * 256 + c0);
    floatx4 res;
#pragma unroll
    for (int j = 0; j < 4; ++j) {
        float y = d[j] * inv * gm[j] + bt[j];
        y = fmaxf(y, 0.0f);
        res[j] = xr[j] + y;
    }
    *(floatx4*)(inout + (size_t)v * 256 + c0) = res;
}

extern "C" void kernel_launch(void* const* d_in, const int* in_sizes, int n_in,
                              void* d_out, int out_size, void* d_ws, size_t ws_size,
                              hipStream_t stream) {
    const float* x       = (const float*)d_in[0];
    const int*   src     = (const int*)d_in[1];
    const int*   dst     = (const int*)d_in[2];
    const float* W_w     = (const float*)d_in[3];
    const float* W_b     = (const float*)d_in[4];
    const float* U_w     = (const float*)d_in[5];
    const float* U_b     = (const float*)d_in[6];
    const float* V_w     = (const float*)d_in[7];
    const float* V_b     = (const float*)d_in[8];
    const float* attn_l  = (const float*)d_in[9];
    const float* attn_r  = (const float*)d_in[10];
    const float* gamma   = (const float*)d_in[11];
    const float* beta    = (const float*)d_in[12];

    char* ws = (char*)d_ws;
    size_t off = 0;
    auto alloc = [&](size_t bytes) -> char* {
        char* p = ws + off;
        off += (bytes + 255) & ~(size_t)255;
        return p;
    };
    u16* WVh     = (u16*)alloc((size_t)NN * 512 * 2);     // Wh | Vh interleaved per node
    u16* wT      = (u16*)alloc((size_t)768 * 256 * 2);
    int* deg     = (int*)alloc((size_t)NN * 4);
    int* rows    = (int*)alloc((size_t)(NN + 1) * 4);
    int* cursor  = (int*)alloc((size_t)NN * 4);
    int* esrc    = (int*)alloc((size_t)NE * 4);
    int* bsum    = (int*)alloc((size_t)NB * 4);
    int* bpre    = (int*)alloc((size_t)NB * 4);
    u16* xbf     = (u16*)alloc((size_t)NROWPAD * 256 * 2);   // optional (last)
    bool use_bf  = (ws_size >= off);

    float* Uh_f32 = (float*)d_out;   // staged in d_out, overwritten by node_kernel

    hipMemsetAsync(deg, 0, (size_t)NN * 4, stream);

    if (use_bf) {
        prep_kernel<<<XCVT_BLOCKS + TW_BLOCKS + HIST_BLOCKS, 256, 0, stream>>>(
            x, xbf, W_w, U_w, V_w, wT, dst, deg);
    } else {
        // no room for xbf: still do tw + hist fused (xcvt blocks write nothing useful)
        prep_kernel<<<XCVT_BLOCKS + TW_BLOCKS + HIST_BLOCKS, 256, 0, stream>>>(
            x, (u16*)wT /*dummy, overwritten later? no - see below*/, W_w, U_w, V_w, wT, dst, deg);
    }

    scanA_kernel<<<NB, 256, 0, stream>>>(deg, bsum);
    scanB_kernel<<<1, 256, 0, stream>>>(bsum, bpre, rows + NN);
    scanC_kernel<<<NB, 256, 0, stream>>>(deg, bpre, rows, cursor);

    int gs_blocks = SCAT_BLOCKS + GEMM_BLOCKS;
    if (use_bf) {
        gemmsc_kernel<true><<<gs_blocks, 256, 0, stream>>>(
            xbf, x, wT, W_b, U_b, V_b, WVh, Uh_f32, src, dst, cursor, esrc);
    } else {
        gemmsc_kernel<false><<<gs_blocks, 256, 0, stream>>>(
            nullptr, x, wT, W_b, U_b, V_b, WVh, Uh_f32, src, dst, cursor, esrc);
    }

    node_kernel<<<(NN + 3) / 4, 256, 0, stream>>>(
        WVh, x, rows, esrc, attn_l, attn_r, gamma, beta, (float*)d_out);
}